// Round 8
// baseline (831.485 us; speedup 1.0000x reference)
//
#include <hip/hip_runtime.h>
#include <hip/hip_bf16.h>

#define NN 8192
#define DD 512

typedef unsigned short u16;
typedef __bf16 bf16_t;
typedef bf16_t bf16x8 __attribute__((ext_vector_type(8)));
typedef float f32x4 __attribute__((ext_vector_type(4)));

__device__ __forceinline__ float bf2f(u16 h) {
    union { unsigned u; float f; } v; v.u = ((unsigned)h) << 16; return v.f;
}
__device__ __forceinline__ u16 f2bf(float f) {
    union { float f; unsigned u; } v; v.f = f;
    unsigned r = v.u + 0x7fffu + ((v.u >> 16) & 1u);
    return (u16)(r >> 16);
}

// fp32 -> bf16, 8 elems/thread (all tensor sizes are multiples of 2048).
__global__ __launch_bounds__(256) void cvt_kernel(const float* __restrict__ s,
        u16* __restrict__ d, int n) {
    int i = (blockIdx.x * 256 + threadIdx.x) * 8;
    if (i >= n) return;
    float4 a = *(const float4*)(s + i);
    float4 b = *(const float4*)(s + i + 4);
    ushort4 o0 = make_ushort4(f2bf(a.x), f2bf(a.y), f2bf(a.z), f2bf(a.w));
    ushort4 o1 = make_ushort4(f2bf(b.x), f2bf(b.y), f2bf(b.z), f2bf(b.w));
    *(ushort4*)(d + i) = o0;
    *(ushort4*)(d + i + 4) = o1;
}

// C[M][Nc] = act(A[M][K] @ B[Nc][K]^T + bias). bf16 in, fp32 accum, bf16/fp32 out.
// m97-class async staging: global_load_lds width=16, 128x128 tile, BK=32,
// 256 thr = 4 waves (2x2), wave tile 64x64 = 4x4 MFMA 16x16x32.
template<bool RELU, bool BIAS, bool F32OUT>
__global__ __launch_bounds__(256) void gemm_bt(const u16* __restrict__ A,
        const u16* __restrict__ B, const float* __restrict__ bias,
        void* __restrict__ Cv, int M, int Nc, int K) {
    __shared__ alignas(16) u16 As[128 * 32];
    __shared__ alignas(16) u16 Bs[128 * 32];
    const int t = threadIdx.x;
    const int lane = t & 63;
    const int wave = t >> 6;
    const int wm = (wave >> 1) * 64;
    const int wn = (wave & 1) * 64;
    const int rowA = blockIdx.y * 128;
    const int rowB = blockIdx.x * 128;

    f32x4 acc[4][4] = {};

    const int mrow = lane & 15;
    const int kk = (lane >> 4) * 8;

    for (int k0 = 0; k0 < K; k0 += 32) {
        __syncthreads();
        #pragma unroll
        for (int r = 0; r < 2; ++r) {
            int chunk = r * 256 + t;
            const u16* srcA = A + (size_t)(rowA + (chunk >> 2)) * K + k0 + (chunk & 3) * 8;
            __builtin_amdgcn_global_load_lds(
                (const __attribute__((address_space(1))) void*)srcA,
                (__attribute__((address_space(3))) void*)(As + chunk * 8), 16, 0, 0);
            const u16* srcB = B + (size_t)(rowB + (chunk >> 2)) * K + k0 + (chunk & 3) * 8;
            __builtin_amdgcn_global_load_lds(
                (const __attribute__((address_space(1))) void*)srcB,
                (__attribute__((address_space(3))) void*)(Bs + chunk * 8), 16, 0, 0);
        }
        __syncthreads();
        bf16x8 af[4], bfv[4];
        #pragma unroll
        for (int i = 0; i < 4; ++i)
            af[i] = *(const bf16x8*)(As + (wm + i * 16 + mrow) * 32 + kk);
        #pragma unroll
        for (int j = 0; j < 4; ++j)
            bfv[j] = *(const bf16x8*)(Bs + (wn + j * 16 + mrow) * 32 + kk);
        #pragma unroll
        for (int i = 0; i < 4; ++i)
            #pragma unroll
            for (int j = 0; j < 4; ++j)
                acc[i][j] = __builtin_amdgcn_mfma_f32_16x16x32_bf16(af[i], bfv[j], acc[i][j], 0, 0, 0);
    }

    // C/D layout (m89/m91): col = lane&15, row = (lane>>4)*4 + reg
    const int crow0 = rowA + wm + (lane >> 4) * 4;
    const int ccol0 = rowB + wn + (lane & 15);
    #pragma unroll
    for (int j = 0; j < 4; ++j) {
        int col = ccol0 + j * 16;
        float bv = BIAS ? bias[col] : 0.0f;
        #pragma unroll
        for (int i = 0; i < 4; ++i) {
            #pragma unroll
            for (int r = 0; r < 4; ++r) {
                float v = acc[i][j][r] + bv;
                if (RELU) v = fmaxf(v, 0.0f);
                size_t off = (size_t)(crow0 + i * 16 + r) * Nc + col;
                if (F32OUT) ((float*)Cv)[off] = v;
                else        ((u16*)Cv)[off] = f2bf(v);
            }
        }
    }
}

// LayerNorm over D=512; y bf16, g/b fp32; writes seq[n][modality][512] bf16.
__global__ __launch_bounds__(256) void ln_kernel(const u16* __restrict__ y,
        const float* __restrict__ g, const float* __restrict__ b,
        u16* __restrict__ seq, int modality) {
    __shared__ float sred[4];
    int n = blockIdx.x, t = threadIdx.x;
    const u16* yr = y + (size_t)n * DD;
    float x0 = bf2f(yr[t]), x1 = bf2f(yr[t + 256]);
    float s = x0 + x1;
    for (int off = 32; off; off >>= 1) s += __shfl_xor(s, off);
    if ((t & 63) == 0) sred[t >> 6] = s;
    __syncthreads();
    float mean = (sred[0] + sred[1] + sred[2] + sred[3]) * (1.0f / DD);
    __syncthreads();
    float d0 = x0 - mean, d1 = x1 - mean;
    float vs = d0 * d0 + d1 * d1;
    for (int off = 32; off; off >>= 1) vs += __shfl_xor(vs, off);
    if ((t & 63) == 0) sred[t >> 6] = vs;
    __syncthreads();
    float var = (sred[0] + sred[1] + sred[2] + sred[3]) * (1.0f / DD);
    float inv = rsqrtf(var + 1e-5f);
    u16* out = seq + (size_t)n * (2 * DD) + modality * DD;
    out[t]       = f2bf(d0 * inv * g[t]       + b[t]);
    out[t + 256] = f2bf(d1 * inv * g[t + 256] + b[t + 256]);
}

// MHA over 2 tokens, 8 heads of 64. One wave per (node, head). ctxm = mean_t(ctx_t).
__global__ __launch_bounds__(256) void attn_kernel(const u16* __restrict__ qkv,
        u16* __restrict__ ctxm) {
    int gid = blockIdx.x * 4 + (threadIdx.x >> 6);
    int lane = threadIdx.x & 63;
    int n = gid >> 3, h = gid & 7;
    const u16* r0 = qkv + (size_t)(n * 2) * 1536;
    const u16* r1 = r0 + 1536;
    float q0 = bf2f(r0[h * 64 + lane]);
    float k0 = bf2f(r0[512 + h * 64 + lane]);
    float v0 = bf2f(r0[1024 + h * 64 + lane]);
    float q1 = bf2f(r1[h * 64 + lane]);
    float k1 = bf2f(r1[512 + h * 64 + lane]);
    float v1 = bf2f(r1[1024 + h * 64 + lane]);
    float p00 = q0 * k0, p01 = q0 * k1, p10 = q1 * k0, p11 = q1 * k1;
    for (int off = 32; off; off >>= 1) {
        p00 += __shfl_xor(p00, off);
        p01 += __shfl_xor(p01, off);
        p10 += __shfl_xor(p10, off);
        p11 += __shfl_xor(p11, off);
    }
    const float sc = 0.125f;  // 1/sqrt(64)
    float s00 = p00 * sc, s01 = p01 * sc, s10 = p10 * sc, s11 = p11 * sc;
    float m0 = fmaxf(s00, s01), e00 = __expf(s00 - m0), e01 = __expf(s01 - m0);
    float a00 = e00 / (e00 + e01), a01 = e01 / (e00 + e01);
    float m1 = fmaxf(s10, s11), e10 = __expf(s10 - m1), e11 = __expf(s11 - m1);
    float a10 = e10 / (e10 + e11), a11 = e11 / (e10 + e11);
    float c0 = a00 * v0 + a01 * v1;
    float c1 = a10 * v0 + a11 * v1;
    ctxm[(size_t)n * 512 + h * 64 + lane] = f2bf(0.5f * (c0 + c1));
}

// Top-16 + softmax stats. ONE WAVE PER ROW (4 rows/block). No LDS, no barriers.
// 128 values/lane in registers (static indexing only), per-lane top-2 tracked;
// 16 shfl-ladder argmax rounds; masked register rescan only on 3rd+ win of a lane.
__global__ __launch_bounds__(256, 1) void topk_wave(const float* __restrict__ S,
        float* __restrict__ topv, int* __restrict__ topi) {
    const float NEG = -__builtin_inff();
    int row = blockIdx.x * 4 + (threadIdx.x >> 6);
    int lane = threadIdx.x & 63;
    const float* Sr = S + (size_t)row * NN;

    float4 vals[32];
    float t1v = NEG, t2v = NEG;
    int t1i = 0x7FFFFFFF, t2i = 0x7FFFFFFF;
    #pragma unroll
    for (int p = 0; p < 32; ++p) {
        float4 v = *(const float4*)(Sr + p * 256 + lane * 4);
        vals[p] = v;
        #pragma unroll
        for (int u = 0; u < 4; ++u) {
            float x = (&v.x)[u];
            int xi = p * 256 + lane * 4 + u;     // ascending -> strict > keeps earliest tie
            bool g1 = x > t1v;
            bool g2 = x > t2v;
            t2v = g1 ? t1v : (g2 ? x : t2v);
            t2i = g1 ? t1i : (g2 ? xi : t2i);
            t1v = g1 ? x : t1v;
            t1i = g1 ? xi : t1i;
        }
    }
    float m = t1v;
    #pragma unroll
    for (int off = 32; off; off >>= 1) m = fmaxf(m, __shfl_xor(m, off));
    float l = 0.0f;
    #pragma unroll
    for (int p = 0; p < 32; ++p)
        l += __expf(vals[p].x - m) + __expf(vals[p].y - m)
           + __expf(vals[p].z - m) + __expf(vals[p].w - m);
    #pragma unroll
    for (int off = 32; off; off >>= 1) l += __shfl_xor(l, off);

    unsigned mk0 = 0, mk1 = 0, mk2 = 0, mk3 = 0;  // removed-slot bits (b = p*4+u)
    float cv = t1v; int ci = t1i;   // current candidate
    float bv = t2v; int bi = t2i;   // backup
    for (int r = 0; r < 16; ++r) {
        float wv = cv; int wi = ci;
        #pragma unroll
        for (int off = 32; off; off >>= 1) {
            float ov = __shfl_xor(wv, off);
            int oi = __shfl_xor(wi, off);
            if (ov > wv || (ov == wv && oi < wi)) { wv = ov; wi = oi; }
        }
        if (lane == 0) {
            topv[(size_t)row * 16 + r] = __expf(wv - m) / l;
            topi[(size_t)row * 16 + r] = wi;
        }
        if (wi == ci) {  // this lane owned the winner (indices unique)
            int b = ((wi >> 8) << 2) | (wi & 3);
            unsigned bit = 1u << (b & 31);
            if (b < 32) mk0 |= bit; else if (b < 64) mk1 |= bit;
            else if (b < 96) mk2 |= bit; else mk3 |= bit;
            cv = bv; ci = bi;
            bv = NEG; bi = 0x7FFFFFFF;
            if (ci == 0x7FFFFFFF) {  // backup exhausted -> masked register rescan
                float nb = NEG; int ni = 0x7FFFFFFF;
                #pragma unroll
                for (int p = 0; p < 32; ++p) {
                    #pragma unroll
                    for (int u = 0; u < 4; ++u) {
                        int bb = p * 4 + u;
                        unsigned w = (bb < 32) ? mk0 : (bb < 64) ? mk1 : (bb < 96) ? mk2 : mk3;
                        float x = ((w >> (bb & 31)) & 1u) ? NEG : (&vals[p].x)[u];
                        if (x > nb) { nb = x; ni = p * 256 + lane * 4 + u; }
                    }
                }
                cv = nb; ci = ni;
            }
        }
    }
}

// H fp32: zero everything, diag = 1.0f. 8 floats/thread.
__global__ __launch_bounds__(256) void zero_diag_f32(float* __restrict__ H) {
    size_t e = ((size_t)blockIdx.x * 256 + threadIdx.x) * 8;
    int r = (int)(e >> 13);
    int c0 = (int)(e & (NN - 1));
    float4 z0 = make_float4(0.f, 0.f, 0.f, 0.f);
    float4 z1 = z0;
    if (r >= c0 && r < c0 + 8) {
        int o = r - c0;
        float* p = (o < 4) ? ((float*)&z0) + o : ((float*)&z1) + (o - 4);
        *p = 1.0f;
    }
    *(float4*)(H + e) = z0;
    *(float4*)(H + e + 4) = z1;
}

__global__ __launch_bounds__(256) void scatter_kernel(const float* __restrict__ topv,
        const int* __restrict__ topi, float* __restrict__ H) {
    int tk = blockIdx.x * 256 + threadIdx.x;  // 8192*16
    int i = tk >> 4;
    int idx = topi[tk];
    H[(size_t)idx * NN + i] = topv[tk];
}

// ew = max(sigmoid(hidden @ w2 + b2), 1e-8), fp32 out. One wave per node.
__global__ __launch_bounds__(256) void ew_kernel(const u16* __restrict__ hidden,
        const float* __restrict__ w2, const float* __restrict__ b2, float* __restrict__ out) {
    int n = blockIdx.x * 4 + (threadIdx.x >> 6);
    int lane = threadIdx.x & 63;
    const u16* hr = hidden + (size_t)n * 256;
    float s = 0.0f;
    #pragma unroll
    for (int p = 0; p < 4; ++p) s += bf2f(hr[lane + p * 64]) * w2[lane + p * 64];
    for (int off = 32; off; off >>= 1) s += __shfl_xor(s, off);
    if (lane == 0) {
        float z = s + b2[0];
        float sig = 1.0f / (1.0f + __expf(-z));
        out[n] = fmaxf(sig, 1e-8f);
    }
}

extern "C" void kernel_launch(void* const* d_in, const int* in_sizes, int n_in,
                              void* d_out, int out_size, void* d_ws, size_t ws_size,
                              hipStream_t stream) {
    const float* x0    = (const float*)d_in[0];
    const float* x1    = (const float*)d_in[1];
    const float* w_p0  = (const float*)d_in[2];
    const float* b_p0  = (const float*)d_in[3];
    const float* g0    = (const float*)d_in[4];
    const float* beta0 = (const float*)d_in[5];
    const float* w_p1  = (const float*)d_in[6];
    const float* b_p1  = (const float*)d_in[7];
    const float* g1    = (const float*)d_in[8];
    const float* beta1 = (const float*)d_in[9];
    const float* in_w  = (const float*)d_in[10];
    const float* in_b  = (const float*)d_in[11];
    const float* out_w = (const float*)d_in[12];
    const float* out_b = (const float*)d_in[13];
    const float* ew_w1 = (const float*)d_in[14];
    const float* ew_b1 = (const float*)d_in[15];
    const float* ew_w2 = (const float*)d_in[16];
    const float* ew_b2 = (const float*)d_in[17];

    float* Hf = (float*)d_out;                  // [8192][8192] fp32 (256 MB)
    float* ew_out = Hf + (size_t)NN * NN;       // [8192] fp32

    // bf16 staging inside the fp32 H region (dead before S fp32 overwrites all of H).
    u16* Hu = (u16*)d_out;
    u16* x0b    = Hu;                           //   0.. 8 MB
    u16* x1b    = Hu + 4194304;                 //   8..16 MB
    u16* y0     = Hu + 8388608;                 //  16..24 MB
    u16* y1     = Hu + 12582912;                //  24..32 MB
    u16* seq    = Hu + 16777216;                //  32..48 MB   [16384][512]
    u16* qkv    = Hu + 25165824;                //  48..96 MB   [16384][1536]
    u16* ctxm   = Hu + 50331648;                //  96..104 MB
    u16* hidden = Hu + 54525952;                // 104..108 MB  [8192][256]
    u16* wp0b   = Hu + 60817408;                // 116 MB.. weights (3.25 MB)
    u16* wp1b   = wp0b + 262144;
    u16* inwb   = wp1b + 262144;                // [1536][512]
    u16* outwb  = inwb + 786432;
    u16* eww1b  = outwb + 262144;               // [256][512]
    // ws: survives the S GEMM (9 MB)
    char* ws = (char*)d_ws;
    u16* fusedB = (u16*)ws;                     // [8192][512] bf16, 8 MB
    float* topv = (float*)(ws + (8u << 20));    // [8192][16]
    int*   topi = (int*)(ws + (8u << 20) + 524288);

    dim3 blk(256);
    // 0: fp32 -> bf16 for all MFMA operands
    cvt_kernel<<<dim3(2048), blk, 0, stream>>>(x0, x0b, 4194304);
    cvt_kernel<<<dim3(2048), blk, 0, stream>>>(x1, x1b, 4194304);
    cvt_kernel<<<dim3(128),  blk, 0, stream>>>(w_p0, wp0b, 262144);
    cvt_kernel<<<dim3(128),  blk, 0, stream>>>(w_p1, wp1b, 262144);
    cvt_kernel<<<dim3(384),  blk, 0, stream>>>(in_w, inwb, 786432);
    cvt_kernel<<<dim3(128),  blk, 0, stream>>>(out_w, outwb, 262144);
    cvt_kernel<<<dim3(64),   blk, 0, stream>>>(ew_w1, eww1b, 131072);
    // 1-2: modality projections (relu fused)
    gemm_bt<true, true, false><<<dim3(4, 64), blk, 0, stream>>>(x0b, wp0b, b_p0, y0, NN, DD, DD);
    gemm_bt<true, true, false><<<dim3(4, 64), blk, 0, stream>>>(x1b, wp1b, b_p1, y1, NN, DD, DD);
    // 3-4: LayerNorm -> seq
    ln_kernel<<<dim3(NN), blk, 0, stream>>>(y0, g0, beta0, seq, 0);
    ln_kernel<<<dim3(NN), blk, 0, stream>>>(y1, g1, beta1, seq, 1);
    // 5: qkv = seq @ in_w^T + in_b  (M=16384, N=1536)
    gemm_bt<false, true, false><<<dim3(12, 128), blk, 0, stream>>>(seq, inwb, in_b, qkv, 2 * NN, 1536, DD);
    // 6: attention -> ctxm = mean_t ctx
    attn_kernel<<<dim3(NN * 8 / 4), blk, 0, stream>>>(qkv, ctxm);
    // 7: fused = ctxm @ out_w^T + out_b (out-proj commutes with token mean)
    gemm_bt<false, true, false><<<dim3(4, 64), blk, 0, stream>>>(ctxm, outwb, out_b, fusedB, NN, DD, DD);
    // 8: hidden = relu(fused @ ew_w1^T + ew_b1)
    gemm_bt<true, true, false><<<dim3(2, 64), blk, 0, stream>>>(fusedB, eww1b, ew_b1, hidden, NN, 256, DD);
    // 9: ew -> fp32 tail of d_out
    ew_kernel<<<dim3(NN / 4), blk, 0, stream>>>(hidden, ew_w2, ew_b2, ew_out);
    // 10: S = fused @ fused^T, fp32, into the FULL H region (staging all dead)
    gemm_bt<false, false, true><<<dim3(64, 64), blk, 0, stream>>>(fusedB, fusedB, nullptr, Hf, NN, NN, DD);
    // 11: per-row softmax stats + top-16 (wave per row, register-resident, no barriers)
    topk_wave<<<dim3(NN / 4), blk, 0, stream>>>(Hf, topv, topi);
    // 12: H := 0 (fp32), diag := 1.0f
    zero_diag_f32<<<dim3(NN * NN / 8 / 256), blk, 0, stream>>>(Hf);
    // 13: H[idx[i,j], i] = vals[i,j]
    scatter_kernel<<<dim3(NN * 16 / 256), blk, 0, stream>>>(topv, topi, Hf);
}

// Round 9
// 700.963 us; speedup vs baseline: 1.1862x; 1.1862x over previous
//
#include <hip/hip_runtime.h>
#include <hip/hip_bf16.h>

#define NN 8192
#define DD 512

typedef unsigned short u16;
typedef __bf16 bf16_t;
typedef bf16_t bf16x8 __attribute__((ext_vector_type(8)));
typedef float f32x4 __attribute__((ext_vector_type(4)));

__device__ __forceinline__ float bf2f(u16 h) {
    union { unsigned u; float f; } v; v.u = ((unsigned)h) << 16; return v.f;
}
__device__ __forceinline__ float bflo(unsigned u) {
    union { unsigned u; float f; } v; v.u = u << 16; return v.f;
}
__device__ __forceinline__ float bfhi(unsigned u) {
    union { unsigned u; float f; } v; v.u = u & 0xFFFF0000u; return v.f;
}
__device__ __forceinline__ u16 f2bf(float f) {
    union { float f; unsigned u; } v; v.f = f;
    unsigned r = v.u + 0x7fffu + ((v.u >> 16) & 1u);
    return (u16)(r >> 16);
}

// Fused fp32->bf16 convert of the 7 GEMM operands, 8 elems/thread.
// Segments (elems): x0 4194304, x1 4194304, w_p0 262144, w_p1 262144,
// in_w 786432, out_w 262144, ew_w1 131072. Total 10092544 = 4928 * 2048.
__global__ __launch_bounds__(256) void cvt7(
        const float* __restrict__ s0, u16* __restrict__ d0,
        const float* __restrict__ s1, u16* __restrict__ d1,
        const float* __restrict__ s2, u16* __restrict__ d2,
        const float* __restrict__ s3, u16* __restrict__ d3,
        const float* __restrict__ s4, u16* __restrict__ d4,
        const float* __restrict__ s5, u16* __restrict__ d5,
        const float* __restrict__ s6, u16* __restrict__ d6) {
    size_t v = ((size_t)blockIdx.x * 256 + threadIdx.x) * 8;
    const float* s; u16* d; size_t off;
    if (v < 4194304)      { s = s0; d = d0; off = v; }
    else if (v < 8388608) { s = s1; d = d1; off = v - 4194304; }
    else if (v < 8650752) { s = s2; d = d2; off = v - 8388608; }
    else if (v < 8912896) { s = s3; d = d3; off = v - 8650752; }
    else if (v < 9699328) { s = s4; d = d4; off = v - 8912896; }
    else if (v < 9961472) { s = s5; d = d5; off = v - 9699328; }
    else                  { s = s6; d = d6; off = v - 9961472; }
    float4 a = *(const float4*)(s + off);
    float4 b = *(const float4*)(s + off + 4);
    ushort4 o0 = make_ushort4(f2bf(a.x), f2bf(a.y), f2bf(a.z), f2bf(a.w));
    ushort4 o1 = make_ushort4(f2bf(b.x), f2bf(b.y), f2bf(b.z), f2bf(b.w));
    *(ushort4*)(d + off) = o0;
    *(ushort4*)(d + off + 4) = o1;
}

// C[M][Nc] = act(A[M][K] @ B[Nc][K]^T + bias). bf16 in, fp32 accum, bf16/fp32 out.
// m97-class async staging: global_load_lds width=16, 128x128 tile, BK=32,
// 256 thr = 4 waves (2x2), wave tile 64x64 = 4x4 MFMA 16x16x32.
template<bool RELU, bool BIAS, bool F32OUT>
__global__ __launch_bounds__(256) void gemm_bt(const u16* __restrict__ A,
        const u16* __restrict__ B, const float* __restrict__ bias,
        void* __restrict__ Cv, int M, int Nc, int K) {
    __shared__ alignas(16) u16 As[128 * 32];
    __shared__ alignas(16) u16 Bs[128 * 32];
    const int t = threadIdx.x;
    const int lane = t & 63;
    const int wave = t >> 6;
    const int wm = (wave >> 1) * 64;
    const int wn = (wave & 1) * 64;
    const int rowA = blockIdx.y * 128;
    const int rowB = blockIdx.x * 128;

    f32x4 acc[4][4] = {};

    const int mrow = lane & 15;
    const int kk = (lane >> 4) * 8;

    for (int k0 = 0; k0 < K; k0 += 32) {
        __syncthreads();
        #pragma unroll
        for (int r = 0; r < 2; ++r) {
            int chunk = r * 256 + t;
            const u16* srcA = A + (size_t)(rowA + (chunk >> 2)) * K + k0 + (chunk & 3) * 8;
            __builtin_amdgcn_global_load_lds(
                (const __attribute__((address_space(1))) void*)srcA,
                (__attribute__((address_space(3))) void*)(As + chunk * 8), 16, 0, 0);
            const u16* srcB = B + (size_t)(rowB + (chunk >> 2)) * K + k0 + (chunk & 3) * 8;
            __builtin_amdgcn_global_load_lds(
                (const __attribute__((address_space(1))) void*)srcB,
                (__attribute__((address_space(3))) void*)(Bs + chunk * 8), 16, 0, 0);
        }
        __syncthreads();
        bf16x8 af[4], bfv[4];
        #pragma unroll
        for (int i = 0; i < 4; ++i)
            af[i] = *(const bf16x8*)(As + (wm + i * 16 + mrow) * 32 + kk);
        #pragma unroll
        for (int j = 0; j < 4; ++j)
            bfv[j] = *(const bf16x8*)(Bs + (wn + j * 16 + mrow) * 32 + kk);
        #pragma unroll
        for (int i = 0; i < 4; ++i)
            #pragma unroll
            for (int j = 0; j < 4; ++j)
                acc[i][j] = __builtin_amdgcn_mfma_f32_16x16x32_bf16(af[i], bfv[j], acc[i][j], 0, 0, 0);
    }

    // C/D layout (m89/m91): col = lane&15, row = (lane>>4)*4 + reg
    const int crow0 = rowA + wm + (lane >> 4) * 4;
    const int ccol0 = rowB + wn + (lane & 15);
    #pragma unroll
    for (int j = 0; j < 4; ++j) {
        int col = ccol0 + j * 16;
        float bv = BIAS ? bias[col] : 0.0f;
        #pragma unroll
        for (int i = 0; i < 4; ++i) {
            #pragma unroll
            for (int r = 0; r < 4; ++r) {
                float v = acc[i][j][r] + bv;
                if (RELU) v = fmaxf(v, 0.0f);
                size_t off = (size_t)(crow0 + i * 16 + r) * Nc + col;
                if (F32OUT) ((float*)Cv)[off] = v;
                else        ((u16*)Cv)[off] = f2bf(v);
            }
        }
    }
}

// LayerNorm over D=512; y bf16, g/b fp32; writes seq[n][modality][512] bf16.
__global__ __launch_bounds__(256) void ln_kernel(const u16* __restrict__ y,
        const float* __restrict__ g, const float* __restrict__ b,
        u16* __restrict__ seq, int modality) {
    __shared__ float sred[4];
    int n = blockIdx.x, t = threadIdx.x;
    const u16* yr = y + (size_t)n * DD;
    float x0 = bf2f(yr[t]), x1 = bf2f(yr[t + 256]);
    float s = x0 + x1;
    for (int off = 32; off; off >>= 1) s += __shfl_xor(s, off);
    if ((t & 63) == 0) sred[t >> 6] = s;
    __syncthreads();
    float mean = (sred[0] + sred[1] + sred[2] + sred[3]) * (1.0f / DD);
    __syncthreads();
    float d0 = x0 - mean, d1 = x1 - mean;
    float vs = d0 * d0 + d1 * d1;
    for (int off = 32; off; off >>= 1) vs += __shfl_xor(vs, off);
    if ((t & 63) == 0) sred[t >> 6] = vs;
    __syncthreads();
    float var = (sred[0] + sred[1] + sred[2] + sred[3]) * (1.0f / DD);
    float inv = rsqrtf(var + 1e-5f);
    u16* out = seq + (size_t)n * (2 * DD) + modality * DD;
    out[t]       = f2bf(d0 * inv * g[t]       + b[t]);
    out[t + 256] = f2bf(d1 * inv * g[t + 256] + b[t + 256]);
}

// MHA over 2 tokens, 8 heads of 64. One wave per (node, head). ctxm = mean_t(ctx_t).
__global__ __launch_bounds__(256) void attn_kernel(const u16* __restrict__ qkv,
        u16* __restrict__ ctxm) {
    int gid = blockIdx.x * 4 + (threadIdx.x >> 6);
    int lane = threadIdx.x & 63;
    int n = gid >> 3, h = gid & 7;
    const u16* r0 = qkv + (size_t)(n * 2) * 1536;
    const u16* r1 = r0 + 1536;
    float q0 = bf2f(r0[h * 64 + lane]);
    float k0 = bf2f(r0[512 + h * 64 + lane]);
    float v0 = bf2f(r0[1024 + h * 64 + lane]);
    float q1 = bf2f(r1[h * 64 + lane]);
    float k1 = bf2f(r1[512 + h * 64 + lane]);
    float v1 = bf2f(r1[1024 + h * 64 + lane]);
    float p00 = q0 * k0, p01 = q0 * k1, p10 = q1 * k0, p11 = q1 * k1;
    for (int off = 32; off; off >>= 1) {
        p00 += __shfl_xor(p00, off);
        p01 += __shfl_xor(p01, off);
        p10 += __shfl_xor(p10, off);
        p11 += __shfl_xor(p11, off);
    }
    const float sc = 0.125f;  // 1/sqrt(64)
    float s00 = p00 * sc, s01 = p01 * sc, s10 = p10 * sc, s11 = p11 * sc;
    float m0 = fmaxf(s00, s01), e00 = __expf(s00 - m0), e01 = __expf(s01 - m0);
    float a00 = e00 / (e00 + e01), a01 = e01 / (e00 + e01);
    float m1 = fmaxf(s10, s11), e10 = __expf(s10 - m1), e11 = __expf(s11 - m1);
    float a10 = e10 / (e10 + e11), a11 = e11 / (e10 + e11);
    float c0 = a00 * v0 + a01 * v1;
    float c1 = a10 * v0 + a11 * v1;
    ctxm[(size_t)n * 512 + h * 64 + lane] = f2bf(0.5f * (c0 + c1));
}

// Top-16 + softmax stats over bf16 S. ONE WAVE PER ROW, streaming (no row cache,
// no LDS, no barriers). Per lane: online softmax + exact top-2 over its 128 vals;
// extraction promotes top-2, masked global re-read only on a lane's 3rd+ win
// (expected 0.14/row). Lane candidate is always its exact unremoved local max.
__global__ __launch_bounds__(256) void topk_bf16(const u16* __restrict__ S,
        float* __restrict__ topv, int* __restrict__ topi) {
    const float NEG = -3e38f;
    int row = blockIdx.x * 4 + (threadIdx.x >> 6);
    int lane = threadIdx.x & 63;
    const u16* Sr = S + (size_t)row * NN;

    float m = NEG, l = 0.0f;
    float t1v = NEG, t2v = NEG;
    int t1i = 0x7FFFFFFF, t2i = 0x7FFFFFFF;

    #pragma unroll
    for (int p = 0; p < 16; ++p) {
        uint4 raw = *(const uint4*)(Sr + p * 512 + lane * 8);
        int base = p * 512 + lane * 8;
        #pragma unroll
        for (int q = 0; q < 4; ++q) {
            unsigned w = (&raw.x)[q];
            #pragma unroll
            for (int h = 0; h < 2; ++h) {
                float x = h ? bfhi(w) : bflo(w);
                int xi = base + q * 2 + h;
                if (x > m) { l = l * __expf(m - x) + 1.0f; m = x; }
                else l += __expf(x - m);
                bool g1 = x > t1v, g2 = x > t2v;
                t2v = g1 ? t1v : (g2 ? x : t2v);
                t2i = g1 ? t1i : (g2 ? xi : t2i);
                t1v = g1 ? x : t1v;
                t1i = g1 ? xi : t1i;
            }
        }
    }
    // wave-reduce (m, l)
    #pragma unroll
    for (int off = 32; off; off >>= 1) {
        float om = __shfl_xor(m, off);
        float ol = __shfl_xor(l, off);
        float nm = fmaxf(m, om);
        l = l * __expf(m - nm) + ol * __expf(om - nm);
        m = nm;
    }

    unsigned mk0 = 0, mk1 = 0, mk2 = 0, mk3 = 0;  // removed slots (slot = p*8+u, 128 bits)
    float cv = t1v; int ci = t1i;
    float bv = t2v; int bi = t2i;
    for (int r = 0; r < 16; ++r) {
        float wv = cv; int wi = ci;
        #pragma unroll
        for (int off = 32; off; off >>= 1) {
            float ov = __shfl_xor(wv, off);
            int oi = __shfl_xor(wi, off);
            if (ov > wv || (ov == wv && oi < wi)) { wv = ov; wi = oi; }
        }
        if (lane == 0) {
            topv[(size_t)row * 16 + r] = __expf(wv - m) / l;
            topi[(size_t)row * 16 + r] = wi;
        }
        if (wi == ci) {  // this lane owned the winner (indices unique)
            int slot = ((wi >> 9) << 3) | (wi & 7);
            unsigned bit = 1u << (slot & 31);
            if (slot < 32) mk0 |= bit; else if (slot < 64) mk1 |= bit;
            else if (slot < 96) mk2 |= bit; else mk3 |= bit;
            cv = bv; ci = bi;
            bv = NEG; bi = 0x7FFFFFFF;
            if (ci == 0x7FFFFFFF) {  // masked global re-read of own 256 B segment
                float nb = NEG; int ni = 0x7FFFFFFF;
                #pragma unroll
                for (int p = 0; p < 16; ++p) {
                    uint4 raw = *(const uint4*)(Sr + p * 512 + lane * 8);
                    int base = p * 512 + lane * 8;
                    #pragma unroll
                    for (int q = 0; q < 4; ++q) {
                        unsigned w = (&raw.x)[q];
                        #pragma unroll
                        for (int h = 0; h < 2; ++h) {
                            int sl = p * 8 + q * 2 + h;
                            unsigned mw = (sl < 32) ? mk0 : (sl < 64) ? mk1
                                        : (sl < 96) ? mk2 : mk3;
                            float x = ((mw >> (sl & 31)) & 1u) ? NEG
                                    : (h ? bfhi(w) : bflo(w));
                            if (x > nb) { nb = x; ni = base + q * 2 + h; }
                        }
                    }
                }
                cv = nb; ci = ni;
            }
        }
    }
}

// diag: H[i,i] = 1.0 (after memset-0, before scatter which may overwrite).
__global__ __launch_bounds__(256) void diag_kernel(float* __restrict__ H) {
    int i = blockIdx.x * 256 + threadIdx.x;
    H[(size_t)i * NN + i] = 1.0f;
}

__global__ __launch_bounds__(256) void scatter_kernel(const float* __restrict__ topv,
        const int* __restrict__ topi, float* __restrict__ H) {
    int tk = blockIdx.x * 256 + threadIdx.x;  // 8192*16
    int i = tk >> 4;
    int idx = topi[tk];
    H[(size_t)idx * NN + i] = topv[tk];
}

// ew = max(sigmoid(hidden @ w2 + b2), 1e-8), fp32 out. One wave per node.
__global__ __launch_bounds__(256) void ew_kernel(const u16* __restrict__ hidden,
        const float* __restrict__ w2, const float* __restrict__ b2, float* __restrict__ out) {
    int n = blockIdx.x * 4 + (threadIdx.x >> 6);
    int lane = threadIdx.x & 63;
    const u16* hr = hidden + (size_t)n * 256;
    float s = 0.0f;
    #pragma unroll
    for (int p = 0; p < 4; ++p) s += bf2f(hr[lane + p * 64]) * w2[lane + p * 64];
    for (int off = 32; off; off >>= 1) s += __shfl_xor(s, off);
    if (lane == 0) {
        float z = s + b2[0];
        float sig = 1.0f / (1.0f + __expf(-z));
        out[n] = fmaxf(sig, 1e-8f);
    }
}

extern "C" void kernel_launch(void* const* d_in, const int* in_sizes, int n_in,
                              void* d_out, int out_size, void* d_ws, size_t ws_size,
                              hipStream_t stream) {
    const float* x0    = (const float*)d_in[0];
    const float* x1    = (const float*)d_in[1];
    const float* w_p0  = (const float*)d_in[2];
    const float* b_p0  = (const float*)d_in[3];
    const float* g0    = (const float*)d_in[4];
    const float* beta0 = (const float*)d_in[5];
    const float* w_p1  = (const float*)d_in[6];
    const float* b_p1  = (const float*)d_in[7];
    const float* g1    = (const float*)d_in[8];
    const float* beta1 = (const float*)d_in[9];
    const float* in_w  = (const float*)d_in[10];
    const float* in_b  = (const float*)d_in[11];
    const float* out_w = (const float*)d_in[12];
    const float* out_b = (const float*)d_in[13];
    const float* ew_w1 = (const float*)d_in[14];
    const float* ew_b1 = (const float*)d_in[15];
    const float* ew_w2 = (const float*)d_in[16];
    const float* ew_b2 = (const float*)d_in[17];

    float* Hf = (float*)d_out;                  // [8192][8192] fp32 (256 MB)
    float* ew_out = Hf + (size_t)NN * NN;       // [8192] fp32

    // bf16 staging inside the fp32 H region (dead before memset rewrites H).
    u16* Hu = (u16*)d_out;
    u16* x0b    = Hu;                           //   0.. 8 MB
    u16* x1b    = Hu + 4194304;                 //   8..16 MB
    u16* y0     = Hu + 8388608;                 //  16..24 MB
    u16* y1     = Hu + 12582912;                //  24..32 MB
    u16* seq    = Hu + 16777216;                //  32..48 MB   [16384][512]
    u16* qkv    = Hu + 25165824;                //  48..96 MB   [16384][1536]
    u16* ctxm   = Hu + 50331648;                //  96..104 MB
    u16* hidden = Hu + 54525952;                // 104..108 MB  [8192][256]
    u16* wp0b   = Hu + 60817408;                // 116 MB.. weights (3.25 MB)
    u16* wp1b   = wp0b + 262144;
    u16* inwb   = wp1b + 262144;                // [1536][512]
    u16* outwb  = inwb + 786432;
    u16* eww1b  = outwb + 262144;               // [256][512]
    u16* Sb     = Hu + 67108864;                // 128..256 MB  raw scores [8192][8192] bf16
    // ws: survives the S GEMM (9 MB)
    char* ws = (char*)d_ws;
    u16* fusedB = (u16*)ws;                     // [8192][512] bf16, 8 MB
    float* topv = (float*)(ws + (8u << 20));    // [8192][16]
    int*   topi = (int*)(ws + (8u << 20) + 524288);

    dim3 blk(256);
    // 0: fp32 -> bf16 for all MFMA operands (one fused launch)
    cvt7<<<dim3(4928), blk, 0, stream>>>(x0, x0b, x1, x1b, w_p0, wp0b, w_p1, wp1b,
                                         in_w, inwb, out_w, outwb, ew_w1, eww1b);
    // 1-2: modality projections (relu fused)
    gemm_bt<true, true, false><<<dim3(4, 64), blk, 0, stream>>>(x0b, wp0b, b_p0, y0, NN, DD, DD);
    gemm_bt<true, true, false><<<dim3(4, 64), blk, 0, stream>>>(x1b, wp1b, b_p1, y1, NN, DD, DD);
    // 3-4: LayerNorm -> seq
    ln_kernel<<<dim3(NN), blk, 0, stream>>>(y0, g0, beta0, seq, 0);
    ln_kernel<<<dim3(NN), blk, 0, stream>>>(y1, g1, beta1, seq, 1);
    // 5: qkv = seq @ in_w^T + in_b  (M=16384, N=1536)
    gemm_bt<false, true, false><<<dim3(12, 128), blk, 0, stream>>>(seq, inwb, in_b, qkv, 2 * NN, 1536, DD);
    // 6: attention -> ctxm = mean_t ctx
    attn_kernel<<<dim3(NN * 8 / 4), blk, 0, stream>>>(qkv, ctxm);
    // 7: fused = ctxm @ out_w^T + out_b (out-proj commutes with token mean)
    gemm_bt<false, true, false><<<dim3(4, 64), blk, 0, stream>>>(ctxm, outwb, out_b, fusedB, NN, DD, DD);
    // 8: hidden = relu(fused @ ew_w1^T + ew_b1)
    gemm_bt<true, true, false><<<dim3(2, 64), blk, 0, stream>>>(fusedB, eww1b, ew_b1, hidden, NN, 256, DD);
    // 9: ew -> fp32 tail of d_out
    ew_kernel<<<dim3(NN / 4), blk, 0, stream>>>(hidden, ew_w2, ew_b2, ew_out);
    // 10: S = fused @ fused^T (bf16) into upper half of H region
    gemm_bt<false, false, false><<<dim3(64, 64), blk, 0, stream>>>(fusedB, fusedB, nullptr, Sb, NN, NN, DD);
    // 11: per-row softmax stats + top-16 (wave per row, streaming)
    topk_bf16<<<dim3(NN / 4), blk, 0, stream>>>(Sb, topv, topi);
    // 12: H := 0 via memset (5.4 TB/s fill path), then diag := 1.0f
    hipMemsetAsync(Hf, 0, (size_t)NN * NN * sizeof(float), stream);
    diag_kernel<<<dim3(NN / 256), blk, 0, stream>>>(Hf);
    // 13: H[idx[i,j], i] = vals[i,j] (overwrites diag where idx==i, matching ref)
    scatter_kernel<<<dim3(NN * 16 / 256), blk, 0, stream>>>(topv, topi, Hf);
}